// Round 4
// baseline (42861.722 us; speedup 1.0000x reference)
//
#include <hip/hip_runtime.h>
#include <cmath>

// Problem constants
#define T_STEPS 16384
#define D_IN    257
#define H_DIM   512
#define O_DIM   257
#define G4      2048   // 4*H

typedef unsigned long long u64;

// Workspace layout (bytes):
//   [0,     8192) : u64 msgA[2][512]  L2-path mailboxes (same-XCD fast path)
//   [8192, 16384) : u64 msgB[2][512]  MALL-path mirror (correctness fallback)
//   [16384,16448) : u32 ctl[9]: xcnt[8] (per-XCD registration), winner (+32)
//   [16640, ...)  : float x_gates[T][2048]
//   then          : float hs[T][512]
#define WS_CTL_OFF    16384
#define WS_XG_OFF     16640
#define WS_HS_OFF     (WS_XG_OFF + (size_t)T_STEPS * G4 * 4)

__device__ inline float fast_sigmoid(float x) {
    return 1.f / (1.f + __expf(-x));
}
__device__ inline float fast_tanh(float x) {
    float ax = fminf(fabsf(x), 15.f);
    float e  = __expf(2.f * ax);
    float t  = (e - 1.f) / (e + 1.f);
    return copysignf(t, x);
}
__device__ inline float dot4(float4 a, float4 b) {
    return a.x * b.x + a.y * b.y + a.z * b.z + a.w * b.w;
}

// Register pin: forbid rematerialization of weight loads inside the loop.
#define PIN4(v) asm volatile("" : "+v"(v.x), "+v"(v.y), "+v"(v.z), "+v"(v.w))

// ---------------------------------------------------------------------------
// Phase 1: x_gates = stft @ W_ih^T + bias  (R0's proven 64x64 tile version)
// ---------------------------------------------------------------------------
__global__ __launch_bounds__(256) void xgate_gemm(
    const float* __restrict__ stft, const float* __restrict__ W_ih,
    const float* __restrict__ b_ih, const float* __restrict__ b_hh,
    float* __restrict__ xg)
{
    const int tid = threadIdx.x;
    const int tx = tid & 15, ty = tid >> 4;
    const int j0 = blockIdx.x * 64;
    const int t0 = blockIdx.y * 64;

    __shared__ float s_a[64][17];
    __shared__ float s_b[64][17];

    float acc[4][4] = {};

    for (int k0 = 0; k0 < D_IN; k0 += 16) {
        #pragma unroll
        for (int l = 0; l < 4; ++l) {
            int idx = tid + l * 256;
            int r  = idx >> 4;
            int kk = idx & 15;
            int k  = k0 + kk;
            s_a[r][kk] = (k < D_IN) ? stft[(size_t)(t0 + r) * D_IN + k] : 0.f;
            s_b[r][kk] = (k < D_IN) ? W_ih[(size_t)(j0 + r) * D_IN + k] : 0.f;
        }
        __syncthreads();
        #pragma unroll
        for (int kk = 0; kk < 16; ++kk) {
            float a[4], b[4];
            #pragma unroll
            for (int r = 0; r < 4; ++r) a[r] = s_a[ty * 4 + r][kk];
            #pragma unroll
            for (int c = 0; c < 4; ++c) b[c] = s_b[tx * 4 + c][kk];
            #pragma unroll
            for (int r = 0; r < 4; ++r)
                #pragma unroll
                for (int c = 0; c < 4; ++c)
                    acc[r][c] += a[r] * b[c];
        }
        __syncthreads();
    }

    float bias[4];
    #pragma unroll
    for (int c = 0; c < 4; ++c) {
        int j = j0 + tx * 4 + c;
        bias[c] = b_ih[j] + b_hh[j];
    }
    #pragma unroll
    for (int r = 0; r < 4; ++r) {
        int t = t0 + ty * 4 + r;
        #pragma unroll
        for (int c = 0; c < 4; ++c) {
            xg[(size_t)t * G4 + j0 + tx * 4 + c] = acc[r][c] + bias[c];
        }
    }
}

// ---------------------------------------------------------------------------
// Phase 2: persistent sequential LSTM — exact R0 step structure, with the
// inter-block hop moved from the MALL (~650cyc) to ONE XCD's L2 (~200cyc).
//
// Placement: 118 KB LDS forces 1 block/CU; 256 blocks => exactly 32 blocks
// per XCD. Each block reads HW_REG_XCC_ID; per-XCD registration counter;
// first XCD to register all 32 wins (agent CAS); losers exit. The 32
// winners sit on 32 distinct CUs of one XCD, so its L2 is their common
// coherence point: publish = plain global_store_dwordx2 (lands in L2),
// poll = global_load_dwordx2 sc0 (L1-bypass, L2-hit).
//
// Safety: producer dual-publishes to a MALL mirror (sc0 sc1). A consumer
// spinning >32768 iters on the L2 path falls back (sticky) to the mirror —
// placement/coherence surprises degrade to ~R0 speed, never hang.
//
// Wave0's xg prefetch is issued ONE STEP AHEAD (right after detect), so the
// poll's vmcnt(0) drain never waits on the ~900cyc HBM xg load.
// ---------------------------------------------------------------------------
__global__ __launch_bounds__(512, 1) void lstm_seq(
    const float* __restrict__ W_hh, const float* __restrict__ xg,
    float* __restrict__ hs, u64* __restrict__ msg, unsigned* __restrict__ ctl)
{
    __shared__ int   s_pad[28672];       // 112 KB: forces 1 block/CU
    __shared__ float s_h[512];           // wave w stages+reads [64w,64w+64) only
    __shared__ float s_part[2][512];     // [t&1][w*64 + c*16 + j]

    const int tid  = threadIdx.x;        // 0..511

    // ---- XCD claim: become worker g in the winning XCD, or exit ----
    int xcc;
    asm volatile("s_getreg_b32 %0, hwreg(HW_REG_XCC_ID)" : "=s"(xcc));
    xcc &= 7;

    if (tid == 0) {
        int role = -1;
        unsigned idx = __hip_atomic_fetch_add(&ctl[xcc], 1u,
                          __ATOMIC_RELAXED, __HIP_MEMORY_SCOPE_AGENT);
        if (idx < 32) {
            if (idx == 31) {
                unsigned exp0 = 0;
                __hip_atomic_compare_exchange_strong(&ctl[8], &exp0,
                    (unsigned)(xcc + 1), __ATOMIC_RELAXED, __ATOMIC_RELAXED,
                    __HIP_MEMORY_SCOPE_AGENT);
            }
            unsigned wv;
            do {
                wv = __hip_atomic_load(&ctl[8], __ATOMIC_RELAXED,
                                       __HIP_MEMORY_SCOPE_AGENT);
            } while (wv == 0);
            if (wv == (unsigned)(xcc + 1)) role = (int)idx;
        }
        s_pad[0] = role;
    }
    __syncthreads();
    const int g = s_pad[0];
    if (g < 0) return;

    // ---- R0 worker body ----
    const int w    = tid >> 6;           // wave id = col chunk 0..7
    const int lane = tid & 63;
    const int j    = lane >> 2;          // 0..15 h-index within block
    const int c    = lane & 3;           // 0..3 16-col sub-chunk
    const int colb = w * 64 + c * 16;    // this lane's col base

    const float* wbase = W_hh + (size_t)(g * 16 + j) * H_DIM + colb;
    const size_t gstride = (size_t)H_DIM * H_DIM;
    float4 wA0, wA1, wA2, wA3, wB0, wB1, wB2, wB3;
    float4 wC0, wC1, wC2, wC3, wD0, wD1, wD2, wD3;
    {
        const float4* p0 = (const float4*)(wbase);
        const float4* p1 = (const float4*)(wbase + gstride);
        const float4* p2 = (const float4*)(wbase + 2 * gstride);
        const float4* p3 = (const float4*)(wbase + 3 * gstride);
        wA0 = p0[0]; wA1 = p0[1]; wA2 = p0[2]; wA3 = p0[3];
        wB0 = p1[0]; wB1 = p1[1]; wB2 = p1[2]; wB3 = p1[3];
        wC0 = p2[0]; wC1 = p2[1]; wC2 = p2[2]; wC3 = p2[3];
        wD0 = p3[0]; wD1 = p3[1]; wD2 = p3[2]; wD3 = p3[3];
    }
    PIN4(wA0); PIN4(wA1); PIN4(wA2); PIN4(wA3);
    PIN4(wB0); PIN4(wB1); PIN4(wB2); PIN4(wB3);
    PIN4(wC0); PIN4(wC1); PIN4(wC2); PIN4(wC3);
    PIN4(wD0); PIN4(wD1); PIN4(wD2); PIN4(wD3);

    float c_state = 0.f;                 // wave0: state for j'=lane&15 (x4 repl)
    const int t_j = lane & 15;           // wave0 tail: h-index within block

    // Poll addresses: msgA (L2 path) and msgB mirror (+8192 B, MALL path).
    const u64 adA0 = (u64)(uintptr_t)(msg + tid);
    const u64 adA1 = (u64)(uintptr_t)(msg + 512 + tid);
    bool use_fb = false;

    // Wave0: xg prefetch one step ahead (t=0 issued here).
    float xv_next = 0.f;
    if (w == 0)
        xv_next = __builtin_nontemporal_load(
            xg + (size_t)0 * G4 + (lane >> 4) * H_DIM + g * 16 + t_j);

    for (int t = 0; t < T_STEPS; ++t) {
        const unsigned tagt = (unsigned)t;
        const int buf = t & 1;

        const float xv = xv_next;        // loaded last step; long since landed

        // Poll own msg word. Fast path: sc0 load (L1-bypass, same-XCD L2 hit).
        u64 u;
        {
            const u64 adA = buf ? adA1 : adA0;
            if (!use_fb) {
                int spins = 0;
                for (;;) {
                    asm volatile(
                        "global_load_dwordx2 %0, %1, off sc0\n\t"
                        "s_waitcnt vmcnt(0)"
                        : "=v"(u) : "v"(adA) : "memory");
                    if ((unsigned)(u >> 32) == tagt) break;
                    if (++spins > 32768) { use_fb = true; break; }
                }
            }
            if (use_fb) {                 // sticky MALL fallback (mirror mbox)
                const u64 adB = adA + 8192;
                for (;;) {
                    asm volatile(
                        "global_load_dwordx2 %0, %1, off sc0 sc1\n\t"
                        "s_waitcnt vmcnt(0)"
                        : "=v"(u) : "v"(adB) : "memory");
                    if ((unsigned)(u >> 32) == tagt) break;
                }
            }
        }

        // Issue NEXT step's xg prefetch now: its latency hides under this
        // step's compute+barrier+tail, so the next poll drain never waits it.
        if (w == 0) {
            int tn = (t + 1 < T_STEPS) ? t + 1 : t;
            xv_next = __builtin_nontemporal_load(
                xg + (size_t)tn * G4 + (lane >> 4) * H_DIM + g * 16 + t_j);
        }

        // Intra-wave h staging: wave w only touches its own 64-word region.
        s_h[tid] = __uint_as_float((unsigned)u);

        const float4* hv = (const float4*)(s_h + colb);
        float4 h0 = hv[0], h1 = hv[1], h2 = hv[2], h3 = hv[3];

        float p0 = dot4(wA0, h0) + dot4(wA1, h1) + dot4(wA2, h2) + dot4(wA3, h3);
        float p1 = dot4(wB0, h0) + dot4(wB1, h1) + dot4(wB2, h2) + dot4(wB3, h3);
        float p2 = dot4(wC0, h0) + dot4(wC1, h1) + dot4(wC2, h2) + dot4(wC3, h3);
        float p3 = dot4(wD0, h0) + dot4(wD1, h1) + dot4(wD2, h2) + dot4(wD3, h3);

        const bool lo2 = (c < 2);
        float a0 = (lo2 ? p0 : p2) + __shfl_xor(lo2 ? p2 : p0, 2, 64);
        float a1 = (lo2 ? p1 : p3) + __shfl_xor(lo2 ? p3 : p1, 2, 64);
        const bool ev = ((c & 1) == 0);
        float fin = (ev ? a0 : a1) + __shfl_xor(ev ? a1 : a0, 1, 64);

        s_part[buf][w * 64 + c * 16 + j] = fin;

        // lgkm-only barrier: LDS writes visible; NO vmcnt drain.
        asm volatile("s_waitcnt lgkmcnt(0)\n\ts_barrier" ::: "memory");

        if (w == 0) {
            const float* pp = &s_part[buf][0];
            float sum = xv;
            #pragma unroll
            for (int k = 0; k < 8; ++k) sum += pp[k * 64 + lane];

            float gi = __shfl(sum, t_j + 0,  64);
            float gf = __shfl(sum, t_j + 16, 64);
            float gg = __shfl(sum, t_j + 32, 64);
            float go = __shfl(sum, t_j + 48, 64);

            float iv = fast_sigmoid(gi);
            float fv = fast_sigmoid(gf);
            float ov = fast_sigmoid(go);
            float gv = fast_tanh(gg);
            c_state = fv * c_state + iv * gv;     // identical on the 4 gate-lanes
            float hn = ov * fast_tanh(c_state);

            if (lane < 16) {                      // t_j == lane here
                u64 m = ((u64)(tagt + 1) << 32) | (u64)__float_as_uint(hn);
                u64* wpA = msg + (((t + 1) & 1) ? 512 : 0) + (g * 16 + lane);
                u64 aA = (u64)(uintptr_t)wpA;
                u64 aB = aA + 8192;
                // L2 publish first (fast path), then MALL mirror (fallback).
                asm volatile("global_store_dwordx2 %0, %1, off"
                             :: "v"(aA), "v"(m) : "memory");
                asm volatile("global_store_dwordx2 %0, %1, off sc0 sc1"
                             :: "v"(aB), "v"(m) : "memory");
                __builtin_nontemporal_store(hn, hs + (size_t)t * H_DIM + g * 16 + lane);
            }
        }
        // No trailing barrier: s_h is intra-wave; s_part double-buffered —
        // its re-write at t+2 is gated by the barrier at t+1.
    }
}

// ---------------------------------------------------------------------------
// Phase 3: out = log_softmax(hs @ W_out^T + b_out)
// ---------------------------------------------------------------------------
__global__ __launch_bounds__(256) void out_softmax(
    const float* __restrict__ hs, const float* __restrict__ W_out,
    const float* __restrict__ b_out, float* __restrict__ out)
{
    const int tid = threadIdx.x;
    const int t0  = blockIdx.x * 16;

    __shared__ float s_w[257 * 33];
    __shared__ float s_hs[16 * 33];
    __shared__ float s_o[16 * 257];
    __shared__ float s_red[8];

    float acc[16] = {};
    float acc256 = 0.f;

    for (int k0 = 0; k0 < H_DIM; k0 += 32) {
        for (int idx = tid; idx < 257 * 32; idx += 256) {
            int row = idx >> 5, col = idx & 31;
            s_w[row * 33 + col] = W_out[(size_t)row * H_DIM + k0 + col];
        }
        for (int idx = tid; idx < 16 * 32; idx += 256) {
            int row = idx >> 5, col = idx & 31;
            s_hs[row * 33 + col] = hs[(size_t)(t0 + row) * H_DIM + k0 + col];
        }
        __syncthreads();
        #pragma unroll
        for (int kk = 0; kk < 32; ++kk) {
            float w = s_w[tid * 33 + kk];
            #pragma unroll
            for (int r = 0; r < 16; ++r)
                acc[r] += s_hs[r * 33 + kk] * w;
        }
        if (tid < 16) {
            #pragma unroll
            for (int kk = 0; kk < 32; ++kk)
                acc256 += s_w[256 * 33 + kk] * s_hs[tid * 33 + kk];
        }
        __syncthreads();
    }

    float bias_c = b_out[tid];
    #pragma unroll
    for (int r = 0; r < 16; ++r) s_o[r * 257 + tid] = acc[r] + bias_c;
    if (tid < 16) s_o[tid * 257 + 256] = acc256 + b_out[256];
    __syncthreads();

    const int lane = tid & 63, wid = tid >> 6;
    for (int r = 0; r < 16; ++r) {
        float v  = s_o[r * 257 + tid];
        float vx = (tid == 0) ? s_o[r * 257 + 256] : -INFINITY;
        float m = fmaxf(v, vx);
        #pragma unroll
        for (int off = 32; off > 0; off >>= 1) m = fmaxf(m, __shfl_xor(m, off, 64));
        if (lane == 0) s_red[wid] = m;
        __syncthreads();
        m = fmaxf(fmaxf(s_red[0], s_red[1]), fmaxf(s_red[2], s_red[3]));
        float e = expf(v - m) + ((tid == 0) ? expf(vx - m) : 0.f);
        #pragma unroll
        for (int off = 32; off > 0; off >>= 1) e += __shfl_xor(e, off, 64);
        if (lane == 0) s_red[4 + wid] = e;
        __syncthreads();
        float s = s_red[4] + s_red[5] + s_red[6] + s_red[7];
        float lg = logf(s) + m;
        out[(size_t)(t0 + r) * O_DIM + tid] = v - lg;
        if (tid == 0) out[(size_t)(t0 + r) * O_DIM + 256] = vx - lg;
    }
}

// ---------------------------------------------------------------------------
extern "C" void kernel_launch(void* const* d_in, const int* in_sizes, int n_in,
                              void* d_out, int out_size, void* d_ws, size_t ws_size,
                              hipStream_t stream) {
    (void)in_sizes; (void)n_in; (void)out_size; (void)ws_size;

    const float* stft  = (const float*)d_in[0];
    const float* W_ih  = (const float*)d_in[1];
    const float* W_hh  = (const float*)d_in[2];
    const float* b_ih  = (const float*)d_in[3];
    const float* b_hh  = (const float*)d_in[4];
    const float* W_out = (const float*)d_in[5];
    const float* b_out = (const float*)d_in[6];
    float* out = (float*)d_out;

    char* ws = (char*)d_ws;
    u64* msg      = (u64*)ws;
    unsigned* ctl = (unsigned*)(ws + WS_CTL_OFF);
    float* xg     = (float*)(ws + WS_XG_OFF);
    float* hs     = (float*)(ws + WS_HS_OFF);

    // Zero msgA, msgB, ctl (tag 0 + h 0 is exactly the t=0 initial state).
    (void)hipMemsetAsync(ws, 0, WS_XG_OFF, stream);

    xgate_gemm<<<dim3(G4 / 64, T_STEPS / 64), 256, 0, stream>>>(
        stft, W_ih, b_ih, b_hh, xg);
    lstm_seq<<<256, 512, 0, stream>>>(W_hh, xg, hs, msg, ctl);
    out_softmax<<<T_STEPS / 16, 256, 0, stream>>>(hs, W_out, b_out, out);
}

// Round 6
// 28802.438 us; speedup vs baseline: 1.4881x; 1.4881x over previous
//
#include <hip/hip_runtime.h>
#include <cmath>

// Problem constants
#define T_STEPS 16384
#define D_IN    257
#define H_DIM   512
#define O_DIM   257
#define G4      2048   // 4*H

typedef unsigned long long u64;

// Workspace layout (bytes):
//   [0, 8192)    : u64 msg[2][512]  (double-buffered self-validating h msgs)
//                  msg word i = (tag << 32) | float_bits(h[i])
//                  NOTE: line p (128B) == producer p's 16 words, 128B-aligned.
//   [8192, ...)  : float x_gates[T][2048]
//   then         : float hs[T][512]
#define WS_XG_OFF     8192
#define WS_HS_OFF     (8192 + (size_t)T_STEPS * G4 * 4)

__device__ inline float fast_sigmoid(float x) {
    return 1.f / (1.f + __expf(-x));
}
__device__ inline float fast_tanh(float x) {
    float ax = fminf(fabsf(x), 15.f);
    float e  = __expf(2.f * ax);
    float t  = (e - 1.f) / (e + 1.f);
    return copysignf(t, x);
}
__device__ inline float dot4(float4 a, float4 b) {
    return a.x * b.x + a.y * b.y + a.z * b.z + a.w * b.w;
}

// Register pin: forbid rematerialization of weight loads inside the loop.
#define PIN4(v) asm volatile("" : "+v"(v.x), "+v"(v.y), "+v"(v.z), "+v"(v.w))

// ---------------------------------------------------------------------------
// Phase 1: x_gates = stft @ W_ih^T + bias  (R0's proven 64x64 tile version)
// ---------------------------------------------------------------------------
__global__ __launch_bounds__(256) void xgate_gemm(
    const float* __restrict__ stft, const float* __restrict__ W_ih,
    const float* __restrict__ b_ih, const float* __restrict__ b_hh,
    float* __restrict__ xg)
{
    const int tid = threadIdx.x;
    const int tx = tid & 15, ty = tid >> 4;
    const int j0 = blockIdx.x * 64;
    const int t0 = blockIdx.y * 64;

    __shared__ float s_a[64][17];
    __shared__ float s_b[64][17];

    float acc[4][4] = {};

    for (int k0 = 0; k0 < D_IN; k0 += 16) {
        #pragma unroll
        for (int l = 0; l < 4; ++l) {
            int idx = tid + l * 256;
            int r  = idx >> 4;
            int kk = idx & 15;
            int k  = k0 + kk;
            s_a[r][kk] = (k < D_IN) ? stft[(size_t)(t0 + r) * D_IN + k] : 0.f;
            s_b[r][kk] = (k < D_IN) ? W_ih[(size_t)(j0 + r) * D_IN + k] : 0.f;
        }
        __syncthreads();
        #pragma unroll
        for (int kk = 0; kk < 16; ++kk) {
            float a[4], b[4];
            #pragma unroll
            for (int r = 0; r < 4; ++r) a[r] = s_a[ty * 4 + r][kk];
            #pragma unroll
            for (int c = 0; c < 4; ++c) b[c] = s_b[tx * 4 + c][kk];
            #pragma unroll
            for (int r = 0; r < 4; ++r)
                #pragma unroll
                for (int c = 0; c < 4; ++c)
                    acc[r][c] += a[r] * b[c];
        }
        __syncthreads();
    }

    float bias[4];
    #pragma unroll
    for (int c = 0; c < 4; ++c) {
        int j = j0 + tx * 4 + c;
        bias[c] = b_ih[j] + b_hh[j];
    }
    #pragma unroll
    for (int r = 0; r < 4; ++r) {
        int t = t0 + ty * 4 + r;
        #pragma unroll
        for (int c = 0; c < 4; ++c) {
            xg[(size_t)t * G4 + j0 + tx * 4 + c] = acc[r][c] + bias[c];
        }
    }
}

// ---------------------------------------------------------------------------
// Phase 2: persistent sequential LSTM — exact R0 structure, with the poll
// replaced by SENTINEL DETECTION + one-shot fetch.
//
// R0-R4 post-mortem: msg line (16 words) was polled by 512 lanes/round
// (16 words x 32 blocks) -> ~0.8 req/cyc at one MALL bank = saturated;
// producer stores queued behind the spin reads (R1/R2/R4: raising request
// pressure always made it worse; R4 proved polls were L2-hits yet slower).
// Fix: per wave only 4 lanes spin, one sentinel word per producer line
// (32 req/line/round, 16x less). On detect, 32 lanes fetch the wave's 64
// words once and verify EVERY tag (correctness independent of line-write
// atomicity), then stage to s_h. Everything else byte-for-byte R0.
//
// Hang audit (R5 infra failure): tag t+2 can only appear in a slot after
// every block's every wave fetched tag t (publish gated by the per-step
// barrier, which is gated by the fetch) — no overwrite-before-read, no
// lost wakeup; divergent spins are exec-masked loops (lanes retire
// individually); un-drained vmcnt saturates at 63 and back-pressures,
// never hangs; 8 waves x 1 s_barrier per step, parity exact.
// ---------------------------------------------------------------------------
__global__ __launch_bounds__(512, 1) void lstm_seq(
    const float* __restrict__ W_hh, const float* __restrict__ xg,
    float* __restrict__ hs, u64* __restrict__ msg)
{
    const int tid  = threadIdx.x;        // 0..511
    const int g    = blockIdx.x;         // 0..31
    const int w    = tid >> 6;           // wave id = col chunk 0..7
    const int lane = tid & 63;
    const int j    = lane >> 2;          // 0..15 h-index within block
    const int c    = lane & 3;           // 0..3 16-col sub-chunk
    const int colb = w * 64 + c * 16;    // this lane's col base

    // Weights: all 4 gate rows of h-index (g*16+j), 16 cols each.
    const float* wbase = W_hh + (size_t)(g * 16 + j) * H_DIM + colb;
    const size_t gstride = (size_t)H_DIM * H_DIM;  // 512*512 between gates
    float4 wA0, wA1, wA2, wA3, wB0, wB1, wB2, wB3;
    float4 wC0, wC1, wC2, wC3, wD0, wD1, wD2, wD3;
    {
        const float4* p0 = (const float4*)(wbase);
        const float4* p1 = (const float4*)(wbase + gstride);
        const float4* p2 = (const float4*)(wbase + 2 * gstride);
        const float4* p3 = (const float4*)(wbase + 3 * gstride);
        wA0 = p0[0]; wA1 = p0[1]; wA2 = p0[2]; wA3 = p0[3];
        wB0 = p1[0]; wB1 = p1[1]; wB2 = p1[2]; wB3 = p1[3];
        wC0 = p2[0]; wC1 = p2[1]; wC2 = p2[2]; wC3 = p2[3];
        wD0 = p3[0]; wD1 = p3[1]; wD2 = p3[2]; wD3 = p3[3];
    }
    PIN4(wA0); PIN4(wA1); PIN4(wA2); PIN4(wA3);
    PIN4(wB0); PIN4(wB1); PIN4(wB2); PIN4(wB3);
    PIN4(wC0); PIN4(wC1); PIN4(wC2); PIN4(wC3);
    PIN4(wD0); PIN4(wD1); PIN4(wD2); PIN4(wD3);

    __shared__ float s_h[512];           // wave w stages+reads [64w,64w+64) only
    __shared__ float s_part[2][512];     // [t&1][w*64 + c*16 + j]

    u64* slot0 = msg;
    u64* slot1 = msg + 512;

    float c_state = 0.f;                 // wave0: state for j'=lane&15 (x4 repl)
    const int t_j = lane & 15;           // wave0 tail: h-index within block

    // Fetch addresses for this lane (lane<32): words w*64 + 2*lane, +1.
    const u64 fet0_s0 = (u64)(uintptr_t)(slot0 + w * 64 + 2 * (lane & 31));
    const u64 fet0_s1 = (u64)(uintptr_t)(slot1 + w * 64 + 2 * (lane & 31));
    // Sentinel address for this lane (lane<4): word 0 of line 4w+lane.
    u64* sen_s0 = slot0 + (size_t)(4 * w + (lane & 3)) * 16;
    u64* sen_s1 = slot1 + (size_t)(4 * w + (lane & 3)) * 16;

    for (int t = 0; t < T_STEPS; ++t) {
        const unsigned tagt = (unsigned)t;
        const int buf = t & 1;

        // Wave 0 prefetches x_gates (independent of h) before the spin.
        float xv = 0.f;
        if (w == 0)
            xv = __builtin_nontemporal_load(
                xg + (size_t)t * G4 + (lane >> 4) * H_DIM + g * 16 + t_j);

        // ---- Sentinel spin: 4 lanes, 1 word per producer line ----
        if (lane < 4) {
            u64* sp = buf ? sen_s1 : sen_s0;
            u64 s;
            do {
                s = __hip_atomic_load(sp, __ATOMIC_RELAXED,
                                      __HIP_MEMORY_SCOPE_AGENT);
            } while ((unsigned)(s >> 32) != tagt);
        }
        // Wave reconverges once all 4 sentinel lines are published.

        // ---- One-shot fetch + verify + stage: 32 lanes, 2 words each ----
        if (lane < 32) {
            const u64 ad0 = buf ? fet0_s1 : fet0_s0;
            const u64 ad1 = ad0 + 8;
            u64 a, b;
            for (;;) {
                asm volatile(
                    "global_load_dwordx2 %0, %2, off sc0 sc1\n\t"
                    "global_load_dwordx2 %1, %3, off sc0 sc1\n\t"
                    "s_waitcnt vmcnt(0)"
                    : "=&v"(a), "=&v"(b)
                    : "v"(ad0), "v"(ad1)
                    : "memory");
                if ((unsigned)(a >> 32) == tagt && (unsigned)(b >> 32) == tagt)
                    break;   // stale sector: rare, re-fetch (low contention)
            }
            float2 hv2 = make_float2(__uint_as_float((unsigned)a),
                                     __uint_as_float((unsigned)b));
            *(float2*)(s_h + w * 64 + 2 * lane) = hv2;
        }
        // Intra-wave: ds_write -> ds_read ordering within one wave.
        asm volatile("s_waitcnt lgkmcnt(0)" ::: "memory");

        // h slice for this lane: 16 floats (4x b128, broadcast across j).
        const float4* hv = (const float4*)(s_h + colb);
        float4 h0 = hv[0], h1 = hv[1], h2 = hv[2], h3 = hv[3];

        // 4 gate partials over this lane's 16 cols (weights in registers).
        float p0 = dot4(wA0, h0) + dot4(wA1, h1) + dot4(wA2, h2) + dot4(wA3, h3);
        float p1 = dot4(wB0, h0) + dot4(wB1, h1) + dot4(wB2, h2) + dot4(wB3, h3);
        float p2 = dot4(wC0, h0) + dot4(wC1, h1) + dot4(wC2, h2) + dot4(wC3, h3);
        float p3 = dot4(wD0, h0) + dot4(wD1, h1) + dot4(wD2, h2) + dot4(wD3, h3);

        // Exchange-half butterfly over the 4 c-lanes: lane c ends with the
        // full 64-col sum of gate c. 3 shuffles total.
        const bool lo2 = (c < 2);
        float a0 = (lo2 ? p0 : p2) + __shfl_xor(lo2 ? p2 : p0, 2, 64);
        float a1 = (lo2 ? p1 : p3) + __shfl_xor(lo2 ? p3 : p1, 2, 64);
        const bool ev = ((c & 1) == 0);
        float fin = (ev ? a0 : a1) + __shfl_xor(ev ? a1 : a0, 1, 64);

        // Write this wave's partial for row (gate=c, j): 2-way banks = free.
        s_part[buf][w * 64 + c * 16 + j] = fin;

        // lgkm-only barrier: LDS writes visible; NO vmcnt drain (publish
        // stores and xg loads stay in flight).
        asm volatile("s_waitcnt lgkmcnt(0)\n\ts_barrier" ::: "memory");

        if (w == 0) {
            // Sum the 8 per-wave partials for this lane's row (r = lane).
            const float* pp = &s_part[buf][0];
            float sum = xv;
            #pragma unroll
            for (int k = 0; k < 8; ++k) sum += pp[k * 64 + lane];

            // Gather the 4 gates of h-index t_j (rows t_j, +16, +32, +48).
            float gi = __shfl(sum, t_j + 0,  64);
            float gf = __shfl(sum, t_j + 16, 64);
            float gg = __shfl(sum, t_j + 32, 64);
            float go = __shfl(sum, t_j + 48, 64);

            float iv = fast_sigmoid(gi);
            float fv = fast_sigmoid(gf);
            float ov = fast_sigmoid(go);
            float gv = fast_tanh(gg);
            c_state = fv * c_state + iv * gv;     // identical on the 4 gate-lanes
            float hn = ov * fast_tanh(c_state);

            if (lane < 16) {                      // t_j == lane here
                // 16-lane coalesced publish: ONE 128B line per producer.
                u64 m = ((u64)(tagt + 1) << 32) | (u64)__float_as_uint(hn);
                u64* wp = (((t + 1) & 1) ? slot1 : slot0) + (g * 16 + lane);
                __hip_atomic_store(wp, m, __ATOMIC_RELAXED, __HIP_MEMORY_SCOPE_AGENT);
                __builtin_nontemporal_store(hn, hs + (size_t)t * H_DIM + g * 16 + lane);
            }
        }
        // No trailing barrier: s_h is intra-wave; s_part double-buffered —
        // its re-write at t+2 is gated by the barrier at t+1, which wave 0
        // only reaches after finishing its reads of s_part[t&1].
    }
}

// ---------------------------------------------------------------------------
// Phase 3: out = log_softmax(hs @ W_out^T + b_out)
// ---------------------------------------------------------------------------
__global__ __launch_bounds__(256) void out_softmax(
    const float* __restrict__ hs, const float* __restrict__ W_out,
    const float* __restrict__ b_out, float* __restrict__ out)
{
    const int tid = threadIdx.x;
    const int t0  = blockIdx.x * 16;

    __shared__ float s_w[257 * 33];
    __shared__ float s_hs[16 * 33];
    __shared__ float s_o[16 * 257];
    __shared__ float s_red[8];

    float acc[16] = {};
    float acc256 = 0.f;

    for (int k0 = 0; k0 < H_DIM; k0 += 32) {
        for (int idx = tid; idx < 257 * 32; idx += 256) {
            int row = idx >> 5, col = idx & 31;
            s_w[row * 33 + col] = W_out[(size_t)row * H_DIM + k0 + col];
        }
        for (int idx = tid; idx < 16 * 32; idx += 256) {
            int row = idx >> 5, col = idx & 31;
            s_hs[row * 33 + col] = hs[(size_t)(t0 + row) * H_DIM + k0 + col];
        }
        __syncthreads();
        #pragma unroll
        for (int kk = 0; kk < 32; ++kk) {
            float w = s_w[tid * 33 + kk];
            #pragma unroll
            for (int r = 0; r < 16; ++r)
                acc[r] += s_hs[r * 33 + kk] * w;
        }
        if (tid < 16) {
            #pragma unroll
            for (int kk = 0; kk < 32; ++kk)
                acc256 += s_w[256 * 33 + kk] * s_hs[tid * 33 + kk];
        }
        __syncthreads();
    }

    float bias_c = b_out[tid];
    #pragma unroll
    for (int r = 0; r < 16; ++r) s_o[r * 257 + tid] = acc[r] + bias_c;
    if (tid < 16) s_o[tid * 257 + 256] = acc256 + b_out[256];
    __syncthreads();

    const int lane = tid & 63, wid = tid >> 6;
    for (int r = 0; r < 16; ++r) {
        float v  = s_o[r * 257 + tid];
        float vx = (tid == 0) ? s_o[r * 257 + 256] : -INFINITY;
        float m = fmaxf(v, vx);
        #pragma unroll
        for (int off = 32; off > 0; off >>= 1) m = fmaxf(m, __shfl_xor(m, off, 64));
        if (lane == 0) s_red[wid] = m;
        __syncthreads();
        m = fmaxf(fmaxf(s_red[0], s_red[1]), fmaxf(s_red[2], s_red[3]));
        float e = expf(v - m) + ((tid == 0) ? expf(vx - m) : 0.f);
        #pragma unroll
        for (int off = 32; off > 0; off >>= 1) e += __shfl_xor(e, off, 64);
        if (lane == 0) s_red[4 + wid] = e;
        __syncthreads();
        float s = s_red[4] + s_red[5] + s_red[6] + s_red[7];
        float lg = logf(s) + m;
        out[(size_t)(t0 + r) * O_DIM + tid] = v - lg;
        if (tid == 0) out[(size_t)(t0 + r) * O_DIM + 256] = vx - lg;
    }
}

// ---------------------------------------------------------------------------
extern "C" void kernel_launch(void* const* d_in, const int* in_sizes, int n_in,
                              void* d_out, int out_size, void* d_ws, size_t ws_size,
                              hipStream_t stream) {
    (void)in_sizes; (void)n_in; (void)out_size; (void)ws_size;

    const float* stft  = (const float*)d_in[0];
    const float* W_ih  = (const float*)d_in[1];
    const float* W_hh  = (const float*)d_in[2];
    const float* b_ih  = (const float*)d_in[3];
    const float* b_hh  = (const float*)d_in[4];
    const float* W_out = (const float*)d_in[5];
    const float* b_out = (const float*)d_in[6];
    float* out = (float*)d_out;

    char* ws = (char*)d_ws;
    u64* msg  = (u64*)ws;
    float* xg = (float*)(ws + WS_XG_OFF);
    float* hs = (float*)(ws + WS_HS_OFF);

    // Zero both msg slots (tag 0 + h 0 is exactly the t=0 initial state).
    (void)hipMemsetAsync(ws, 0, 8192, stream);

    xgate_gemm<<<dim3(G4 / 64, T_STEPS / 64), 256, 0, stream>>>(
        stft, W_ih, b_ih, b_hh, xg);
    lstm_seq<<<32, 512, 0, stream>>>(W_hh, xg, hs, msg);
    out_softmax<<<T_STEPS / 16, 256, 0, stream>>>(hs, W_out, b_out, out);
}